// Round 12
// baseline (1080.268 us; speedup 1.0000x reference)
//
#include <hip/hip_runtime.h>
#include <cstdint>
#include <cstddef>

#define BB 16
#define NN 4096
#define CC 64
#define MM 1024
#define KK 64
#define HH 128
#define NEGV -1.0e30f

#define FTH 256   // threads per block (4 waves)
#define FPT 16    // fps points per thread (FTH*FPT == NN)
#define NPROD 16  // producer blocks (one per batch)
#define GTOT 512  // total blocks: 2 per CU exactly (LDS limiter), co-residency guaranteed

#define KC1 96    // layer-1 K dim padded (67 -> 96)
#define SA 104    // LDS stride of feat planes
#define SH 136    // LDS stride of h1 planes

typedef __attribute__((ext_vector_type(8))) short bf16x8;
typedef __attribute__((ext_vector_type(4))) float f32x4;

__device__ __forceinline__ unsigned int f2bf(float f) {
  unsigned int u = __float_as_uint(f);
  return (u + 0x7fffu + ((u >> 16) & 1u)) >> 16;
}
__device__ __forceinline__ void split2(float f, unsigned int& h, unsigned int& l) {
  h = f2bf(f);
  float hf = __uint_as_float(h << 16);
  l = f2bf(f - hf);
}

template <int CTRL, int RM>
__device__ __forceinline__ void dpp_max64(unsigned int& hi, unsigned int& lo) {
  unsigned int shi = (unsigned int)__builtin_amdgcn_update_dpp(
      (int)hi, (int)hi, CTRL, RM, 0xf, false);
  unsigned int slo = (unsigned int)__builtin_amdgcn_update_dpp(
      (int)lo, (int)lo, CTRL, RM, 0xf, false);
  unsigned long long cur = ((unsigned long long)hi << 32) | lo;
  unsigned long long oth = ((unsigned long long)shi << 32) | slo;
  if (oth > cur) { hi = shi; lo = slo; }
}

// ---------------------------------------------------------------------------
// pn: |p|^2 per point, exact order (x^2+y^2)+z^2, no FMA.
// ---------------------------------------------------------------------------
__global__ __launch_bounds__(256) void pn_kernel(const float* __restrict__ pos,
                                                 float* __restrict__ pn) {
#pragma clang fp contract(off)
  int i = blockIdx.x * 256 + threadIdx.x;
  if (i < BB * NN) {
    float x = pos[(size_t)i * 3 + 0];
    float y = pos[(size_t)i * 3 + 1];
    float z = pos[(size_t)i * 3 + 2];
    pn[i] = (x * x + y * y) + z * z;
  }
}

// ---------------------------------------------------------------------------
// Weight prep: transpose + pad + bf16 hi/lo split, B-fragment layout [n][k].
// ---------------------------------------------------------------------------
__global__ __launch_bounds__(128) void wprep_kernel(
    const float* __restrict__ W1, const float* __restrict__ W2,
    unsigned short* __restrict__ W1Th, unsigned short* __restrict__ W1Tl,
    unsigned short* __restrict__ W2Th, unsigned short* __restrict__ W2Tl) {
  const int n = blockIdx.x, t = threadIdx.x;
  if (t < KC1) {
    float v = (t < 67) ? W1[(size_t)t * HH + n] : 0.0f;
    unsigned int h, l; split2(v, h, l);
    W1Th[n * KC1 + t] = (unsigned short)h;
    W1Tl[n * KC1 + t] = (unsigned short)l;
  }
  {
    float v = W2[(size_t)t * HH + n];
    unsigned int h, l; split2(v, h, l);
    W2Th[n * HH + t] = (unsigned short)h;
    W2Tl[n * HH + t] = (unsigned short)l;
  }
}

// ---------------------------------------------------------------------------
// init: zero progress[16] + claim (d_ws is 0xAA-poisoned before every launch)
// ---------------------------------------------------------------------------
__global__ void init_kernel(unsigned int* progress, unsigned int* claim) {
  int t = threadIdx.x;
  if (t < NPROD) progress[t] = 0u;
  if (t == NPROD) *claim = 0u;
}

// ---------------------------------------------------------------------------
// FUSED producer-consumer kernel, R12: 512 blocks x 256 threads, 76.3KB LDS
// -> exactly 2 blocks/CU (LDS limiter; __launch_bounds__(256,2) caps VGPR at
// 256 so VGPR can't lower it) -> the whole grid is co-resident regardless of
// dispatch order (no deadlock; producers never wait on consumers).
// Blocks 0..15: R7-exact FPS at s_setprio(3) (protects the VALU-bound FPS
// critical chain from the co-resident consumer block's issue traffic),
// flushing each 8 centers via agent-scope stores + RELEASE progress[b].
// Blocks 16..511 (496 consumers, 2-deep per CU -> latency hidden, capacity
// ~33 centers/us > production ~25/us): claim centers batch-interleaved, spin
// on progress[b] (relaxed + s_sleep), 4-wave ballq + R9 mlp body.
// All numerics bit-identical to R11 (passed at absmax 0.015625).
// ---------------------------------------------------------------------------
__global__ __launch_bounds__(256, 2) void fused_kernel(
    const float* __restrict__ pos, const float* __restrict__ x,
    const float* __restrict__ pn,
    float* __restrict__ pos_s_ws, float* __restrict__ pos_s_out,
    const unsigned short* __restrict__ W1Th, const unsigned short* __restrict__ W1Tl,
    const unsigned short* __restrict__ W2Th, const unsigned short* __restrict__ W2Tl,
    const float* __restrict__ b1, const float* __restrict__ b2,
    float* __restrict__ out,
    unsigned int* __restrict__ progress, unsigned int* __restrict__ claim) {
#pragma clang fp contract(off)
  __shared__ __attribute__((aligned(16))) unsigned char LBUF[78080];
  const int t = threadIdx.x;
  const int lane = t & 63;
  const int wv = t >> 6;

  if (blockIdx.x < NPROD) {
    // =================== PRODUCER: FPS for batch b ===================
    __builtin_amdgcn_s_setprio(3);   // FPS chain wins issue arbitration
    const int b = blockIdx.x;
    float4* P4 = (float4*)LBUF;                          // 65536 B
    float* SXa = (float*)(LBUF + 65536);                 // 4096 B
    float* SYa = (float*)(LBUF + 69632);                 // 4096 B
    float* SZa = (float*)(LBUF + 73728);                 // 4096 B
    unsigned long long* cand = (unsigned long long*)(LBUF + 77824); // [2][4]
    const float* pb = pos + (size_t)b * NN * 3;
    float px[FPT], py[FPT], pz[FPT], dd[FPT];
#pragma unroll
    for (int j = 0; j < FPT; ++j) {
      int i = t + j * FTH;
      float xx = pb[i * 3 + 0], yy = pb[i * 3 + 1], zz = pb[i * 3 + 2];
      P4[i] = make_float4(xx, yy, zz, 0.0f);
      px[j] = xx; py[j] = yy; pz[j] = zz;
      dd[j] = 3.4028234663852886e38f;
    }
    __syncthreads();
    float4 c4 = P4[0];
    float sx = c4.x, sy = c4.y, sz = c4.z;
    if (t == 0) { SXa[0] = sx; SYa[0] = sy; SZa[0] = sz; }

    for (int m = 1; m < MM; ++m) {
      float bv = -1.0f;
      int   bi = 0;
#pragma unroll
      for (int j = 0; j < FPT; ++j) {
        float dx = px[j] - sx, dy = py[j] - sy, dz = pz[j] - sz;
        float d2 = (dx * dx + dy * dy) + dz * dz;   // no FMA (pragma)
        float nd = fminf(dd[j], d2);
        dd[j] = nd;
        if (nd > bv) { bv = nd; bi = t + (j << 8); }
      }
      unsigned int kh = __float_as_uint(bv);
      unsigned int kl = ~(unsigned int)bi;
      dpp_max64<0x111, 0xf>(kh, kl);
      dpp_max64<0x112, 0xf>(kh, kl);
      dpp_max64<0x114, 0xf>(kh, kl);
      dpp_max64<0x118, 0xf>(kh, kl);
      dpp_max64<0x142, 0xa>(kh, kl);
      dpp_max64<0x143, 0xc>(kh, kl);
      if (lane == 63)
        cand[(m & 1) * 4 + wv] = ((unsigned long long)kh << 32) | kl;
      __syncthreads();
      unsigned long long best = cand[(m & 1) * 4 + 0];
#pragma unroll
      for (int w = 1; w < 4; ++w) {
        unsigned long long ok = cand[(m & 1) * 4 + w];
        best = ok > best ? ok : best;
      }
      int fi = (int)(~(unsigned int)(best & 0xffffffffull));
      float4 w4 = P4[fi];
      sx = w4.x; sy = w4.y; sz = w4.z;
      if (t == 0) {
        SXa[m] = sx; SYa[m] = sy; SZa[m] = sz;
        if ((m & 7) == 7) {
          int base = m - 7;
          for (int j = 0; j < 8; ++j) {
            size_t o = ((size_t)b * MM + base + j) * 3;
            float ox = SXa[base + j], oy = SYa[base + j], oz = SZa[base + j];
            __hip_atomic_store(&pos_s_ws[o + 0], ox, __ATOMIC_RELAXED, __HIP_MEMORY_SCOPE_AGENT);
            __hip_atomic_store(&pos_s_ws[o + 1], oy, __ATOMIC_RELAXED, __HIP_MEMORY_SCOPE_AGENT);
            __hip_atomic_store(&pos_s_ws[o + 2], oz, __ATOMIC_RELAXED, __HIP_MEMORY_SCOPE_AGENT);
            pos_s_out[o + 0] = ox; pos_s_out[o + 1] = oy; pos_s_out[o + 2] = oz;
          }
          __hip_atomic_store(&progress[b], (unsigned int)(m + 1),
                             __ATOMIC_RELEASE, __HIP_MEMORY_SCOPE_AGENT);
        }
      }
    }
    return;
  }

  // ===================== CONSUMER: ballq + MLP per center =====================
  unsigned short* Ah = (unsigned short*)LBUF;
  unsigned short* Al = (unsigned short*)(LBUF + 64 * SA * 2);
  unsigned short* Hh = (unsigned short*)LBUF;
  unsigned short* Hl = (unsigned short*)(LBUF + 64 * SH * 2);
  int* nbr_s = (int*)(LBUF + 34816);                       // 64 ints
  unsigned long long* masksL = (unsigned long long*)(LBUF + 35072); // 64 u64
  int* prefixL = (int*)(LBUF + 35584);                     // 64 ints
  float* ctr = (float*)(LBUF + 35840);                     // 3 floats
  volatile int* cidShare = (int*)(LBUF + 35856);
  int* cntS = (int*)(LBUF + 35860);
  const int r = lane & 15, q = lane >> 4;
  const int wbase = wv * 32;

  while (true) {
    if (t == 0) {
      unsigned int i = __hip_atomic_fetch_add(claim, 1u, __ATOMIC_RELAXED,
                                              __HIP_MEMORY_SCOPE_AGENT);
      *cidShare = (int)i;
    }
    __syncthreads();
    int i = *cidShare;
    if (i >= BB * MM) break;                       // uniform exit
    const int cid = ((i & 15) << 10) | (i >> 4);   // batch-interleaved order
    const int b = cid >> 10;
    const int m = cid & 1023;

    if (t < 64) {   // wave 0 polls production progress
      while ((int)__hip_atomic_load(&progress[b], __ATOMIC_RELAXED,
                                    __HIP_MEMORY_SCOPE_AGENT) <= m)
        __builtin_amdgcn_s_sleep(32);
    }
    if (t < 3)
      ctr[t] = __hip_atomic_load(&pos_s_ws[(size_t)cid * 3 + t],
                                 __ATOMIC_RELAXED, __HIP_MEMORY_SCOPE_AGENT);
    __syncthreads();

    // ---- ballq: 4-wave mask pass + wave0 prefix + compaction ----
    const float sx = ctr[0], sy = ctr[1], sz = ctr[2];
    const float sn = (sx * sx + sy * sy) + sz * sz;
    const float* pb = pos + (size_t)b * NN * 3;
    const float* pnb = pn + (size_t)b * NN;
#pragma unroll
    for (int cc = 0; cc < 16; ++cc) {
      int c = (wv << 4) + cc;
      int n = (c << 6) + lane;
      float xx = pb[n * 3 + 0], yy = pb[n * 3 + 1], zz = pb[n * 3 + 2];
      float dot = __builtin_fmaf(sz, zz, __builtin_fmaf(sy, yy, sx * xx));
      float d2 = (sn + pnb[n]) - 2.0f * dot;
      bool pred = d2 <= 0.04f;
      unsigned long long mask = __ballot(pred);
      if (lane == 0) masksL[c] = mask;
    }
    __syncthreads();
    if (t < 64) {
      int pc = (int)__popcll(masksL[lane]);
      int incl = pc;
#pragma unroll
      for (int off = 1; off < 64; off <<= 1) {
        int o2 = __shfl_up(incl, off, 64);
        if (lane >= off) incl += o2;
      }
      prefixL[lane] = incl - pc;
      if (lane == 63) *cntS = incl < KK ? incl : KK;
    }
    __syncthreads();
    const int cnt = *cntS;
#pragma unroll
    for (int cc = 0; cc < 16; ++cc) {
      int c = (wv << 4) + cc;
      unsigned long long mk = masksL[c];
      bool pred = (mk >> lane) & 1ull;
      int slot = prefixL[c] + (int)__popcll(mk & ((1ull << lane) - 1ull));
      if (pred && slot < KK) nbr_s[slot] = (c << 6) + lane;
    }
    __syncthreads();

    // ---- gather + hi/lo split into LDS feat planes ----
    {
      const int kn = t >> 2, p = t & 3;
      float vals[16];
      float d0 = 0.0f, d1 = 0.0f, d2v = 0.0f;
      if (kn < cnt) {
        int n = nbr_s[kn];
        const float* xp = x + ((size_t)b * NN + n) * CC + p * 16;
#pragma unroll
        for (int ii = 0; ii < 4; ++ii) {
          float4 v = ((const float4*)xp)[ii];
          vals[ii * 4 + 0] = v.x; vals[ii * 4 + 1] = v.y;
          vals[ii * 4 + 2] = v.z; vals[ii * 4 + 3] = v.w;
        }
        if (p == 0) {
          const float* pp = pos + ((size_t)b * NN + n) * 3;
          d0 = pp[0] - sx; d1 = pp[1] - sy; d2v = pp[2] - sz;
        }
      } else {
#pragma unroll
        for (int ii = 0; ii < 16; ++ii) vals[ii] = 0.0f;
      }
#pragma unroll
      for (int j = 0; j < 16; j += 2) {
        unsigned int h0, l0, h1, l1;
        split2(vals[j], h0, l0);
        split2(vals[j + 1], h1, l1);
        int c = p * 16 + j;
        *(unsigned int*)&Ah[kn * SA + c] = h0 | (h1 << 16);
        *(unsigned int*)&Al[kn * SA + c] = l0 | (l1 << 16);
      }
      if (p == 0) {
        unsigned int h0, l0, h1, l1, h2, l2;
        split2(d0, h0, l0); split2(d1, h1, l1); split2(d2v, h2, l2);
        *(unsigned int*)&Ah[kn * SA + 64] = h0 | (h1 << 16);
        *(unsigned int*)&Al[kn * SA + 64] = l0 | (l1 << 16);
        *(unsigned int*)&Ah[kn * SA + 66] = h2;
        *(unsigned int*)&Al[kn * SA + 66] = l2;
      } else if (p == 1) {
#pragma unroll
        for (int c = 68; c < 80; c += 2) {
          *(unsigned int*)&Ah[kn * SA + c] = 0u;
          *(unsigned int*)&Al[kn * SA + c] = 0u;
        }
      } else if (p == 2) {
#pragma unroll
        for (int c = 80; c < 96; c += 2) {
          *(unsigned int*)&Ah[kn * SA + c] = 0u;
          *(unsigned int*)&Al[kn * SA + c] = 0u;
        }
      }
    }
    __syncthreads();

    f32x4 acc[4][2];
#pragma unroll
    for (int mt = 0; mt < 4; ++mt)
#pragma unroll
      for (int nt = 0; nt < 2; ++nt) acc[mt][nt] = (f32x4)0.0f;

    // ---- layer 1 ----
#pragma unroll
    for (int kc = 0; kc < 3; ++kc) {
      bf16x8 bh[2], bl[2];
#pragma unroll
      for (int nt = 0; nt < 2; ++nt) {
        int o = (wbase + nt * 16 + r) * KC1 + kc * 32 + q * 8;
        bh[nt] = *(const bf16x8*)(W1Th + o);
        bl[nt] = *(const bf16x8*)(W1Tl + o);
      }
#pragma unroll
      for (int mt = 0; mt < 4; ++mt) {
        int o = (mt * 16 + r) * SA + kc * 32 + q * 8;
        bf16x8 ah = *(const bf16x8*)&Ah[o];
        bf16x8 al = *(const bf16x8*)&Al[o];
#pragma unroll
        for (int nt = 0; nt < 2; ++nt) {
          acc[mt][nt] = __builtin_amdgcn_mfma_f32_16x16x32_bf16(ah, bh[nt], acc[mt][nt], 0, 0, 0);
          acc[mt][nt] = __builtin_amdgcn_mfma_f32_16x16x32_bf16(al, bh[nt], acc[mt][nt], 0, 0, 0);
          acc[mt][nt] = __builtin_amdgcn_mfma_f32_16x16x32_bf16(ah, bl[nt], acc[mt][nt], 0, 0, 0);
        }
      }
    }
    __syncthreads();   // alias guard: A-plane reads done before H overwrite

    {
      float b1v[2] = { b1[wbase + r], b1[wbase + 16 + r] };
#pragma unroll
      for (int mt = 0; mt < 4; ++mt)
#pragma unroll
        for (int nt = 0; nt < 2; ++nt)
#pragma unroll
          for (int ii = 0; ii < 4; ++ii) {
            int mm = mt * 16 + q * 4 + ii;
            int n = wbase + nt * 16 + r;
            float v = fmaxf(acc[mt][nt][ii] + b1v[nt], 0.0f);
            unsigned int h, l; split2(v, h, l);
            Hh[mm * SH + n] = (unsigned short)h;
            Hl[mm * SH + n] = (unsigned short)l;
          }
    }
    __syncthreads();

    // ---- layer 2 + masked max ----
#pragma unroll
    for (int mt = 0; mt < 4; ++mt)
#pragma unroll
      for (int nt = 0; nt < 2; ++nt) acc[mt][nt] = (f32x4)0.0f;
#pragma unroll
    for (int kc = 0; kc < 4; ++kc) {
      bf16x8 bh[2], bl[2];
#pragma unroll
      for (int nt = 0; nt < 2; ++nt) {
        int o = (wbase + nt * 16 + r) * HH + kc * 32 + q * 8;
        bh[nt] = *(const bf16x8*)(W2Th + o);
        bl[nt] = *(const bf16x8*)(W2Tl + o);
      }
#pragma unroll
      for (int mt = 0; mt < 4; ++mt) {
        int o = (mt * 16 + r) * SH + kc * 32 + q * 8;
        bf16x8 ah = *(const bf16x8*)&Hh[o];
        bf16x8 al = *(const bf16x8*)&Hl[o];
#pragma unroll
        for (int nt = 0; nt < 2; ++nt) {
          acc[mt][nt] = __builtin_amdgcn_mfma_f32_16x16x32_bf16(ah, bh[nt], acc[mt][nt], 0, 0, 0);
          acc[mt][nt] = __builtin_amdgcn_mfma_f32_16x16x32_bf16(al, bh[nt], acc[mt][nt], 0, 0, 0);
          acc[mt][nt] = __builtin_amdgcn_mfma_f32_16x16x32_bf16(ah, bl[nt], acc[mt][nt], 0, 0, 0);
        }
      }
    }
    {
      float b2v[2] = { b2[wbase + r], b2[wbase + 16 + r] };
#pragma unroll
      for (int nt = 0; nt < 2; ++nt) {
        float vmax = NEGV;
#pragma unroll
        for (int mt = 0; mt < 4; ++mt)
#pragma unroll
          for (int ii = 0; ii < 4; ++ii) {
            int mm = mt * 16 + q * 4 + ii;
            float v = fmaxf(acc[mt][nt][ii] + b2v[nt], 0.0f);
            if (mm < cnt) vmax = fmaxf(vmax, v);
          }
        vmax = fmaxf(vmax, __shfl_xor(vmax, 16, 64));
        vmax = fmaxf(vmax, __shfl_xor(vmax, 32, 64));
        if (q == 0)
          out[(size_t)cid * HH + wbase + nt * 16 + r] = (cnt > 0) ? vmax : 0.0f;
      }
    }
    __syncthreads();   // LDS reuse guard before next center
  }
}

// ---------------------------------------------------------------------------
extern "C" void kernel_launch(void* const* d_in, const int* in_sizes, int n_in,
                              void* d_out, int out_size, void* d_ws, size_t ws_size,
                              hipStream_t stream) {
  const float* x   = (const float*)d_in[0];
  const float* pos = (const float*)d_in[1];
  const float* W1  = (const float*)d_in[2];
  const float* b1  = (const float*)d_in[3];
  const float* W2  = (const float*)d_in[4];
  const float* b2  = (const float*)d_in[5];
  float* out = (float*)d_out;
  float* pos_s_out = out + (size_t)BB * MM * HH;

  char* ws = (char*)d_ws;
  float* pos_s_ws = (float*)(ws);                          // 196608 B
  float* pn       = (float*)(ws + 196608);                 // 262144 B
  unsigned short* W1Th = (unsigned short*)(ws + 458752);   // 24576 B
  unsigned short* W1Tl = (unsigned short*)(ws + 483328);   // 24576 B
  unsigned short* W2Th = (unsigned short*)(ws + 507904);   // 32768 B
  unsigned short* W2Tl = (unsigned short*)(ws + 540672);   // 32768 B
  unsigned int* progress = (unsigned int*)(ws + 573440);   // 64 B
  unsigned int* claim    = (unsigned int*)(ws + 573504);   // 4 B

  wprep_kernel<<<HH, 128, 0, stream>>>(W1, W2, W1Th, W1Tl, W2Th, W2Tl);
  pn_kernel<<<(BB * NN) / 256, 256, 0, stream>>>(pos, pn);
  init_kernel<<<1, 64, 0, stream>>>(progress, claim);
  fused_kernel<<<GTOT, 256, 0, stream>>>(pos, x, pn, pos_s_ws, pos_s_out,
                                         W1Th, W1Tl, W2Th, W2Tl, b1, b2, out,
                                         progress, claim);
}

// Round 13
// 893.054 us; speedup vs baseline: 1.2096x; 1.2096x over previous
//
#include <hip/hip_runtime.h>
#include <cstdint>
#include <cstddef>

#define BB 16
#define NN 4096
#define CC 64
#define MM 1024
#define KK 64
#define HH 128
#define NEGV -1.0e30f

#define FTH 256   // fps active threads (4 waves)
#define FPT 16    // fps points per thread (FTH*FPT == NN)
#define NPROD 16  // producer blocks (one per batch)
#define GTOT 256  // total blocks: 1 per CU exactly (82KB LDS forces it)

#define KC1 96    // layer-1 K dim padded (67 -> 96)
#define SA 104    // LDS stride of feat planes
#define SH 136    // LDS stride of h1 planes
#define HSTRIDE 41984  // per-half consumer LDS region

typedef __attribute__((ext_vector_type(8))) short bf16x8;
typedef __attribute__((ext_vector_type(4))) float f32x4;

__device__ __forceinline__ unsigned int f2bf(float f) {
  unsigned int u = __float_as_uint(f);
  return (u + 0x7fffu + ((u >> 16) & 1u)) >> 16;
}
__device__ __forceinline__ void split2(float f, unsigned int& h, unsigned int& l) {
  h = f2bf(f);
  float hf = __uint_as_float(h << 16);
  l = f2bf(f - hf);
}

template <int CTRL, int RM>
__device__ __forceinline__ void dpp_max64(unsigned int& hi, unsigned int& lo) {
  unsigned int shi = (unsigned int)__builtin_amdgcn_update_dpp(
      (int)hi, (int)hi, CTRL, RM, 0xf, false);
  unsigned int slo = (unsigned int)__builtin_amdgcn_update_dpp(
      (int)lo, (int)lo, CTRL, RM, 0xf, false);
  unsigned long long cur = ((unsigned long long)hi << 32) | lo;
  unsigned long long oth = ((unsigned long long)shi << 32) | slo;
  if (oth > cur) { hi = shi; lo = slo; }
}

// ---------------------------------------------------------------------------
// pn: |p|^2 per point, exact order (x^2+y^2)+z^2, no FMA.
// ---------------------------------------------------------------------------
__global__ __launch_bounds__(256) void pn_kernel(const float* __restrict__ pos,
                                                 float* __restrict__ pn) {
#pragma clang fp contract(off)
  int i = blockIdx.x * 256 + threadIdx.x;
  if (i < BB * NN) {
    float x = pos[(size_t)i * 3 + 0];
    float y = pos[(size_t)i * 3 + 1];
    float z = pos[(size_t)i * 3 + 2];
    pn[i] = (x * x + y * y) + z * z;
  }
}

// ---------------------------------------------------------------------------
// Weight prep: transpose + pad + bf16 hi/lo split, B-fragment layout [n][k].
// ---------------------------------------------------------------------------
__global__ __launch_bounds__(128) void wprep_kernel(
    const float* __restrict__ W1, const float* __restrict__ W2,
    unsigned short* __restrict__ W1Th, unsigned short* __restrict__ W1Tl,
    unsigned short* __restrict__ W2Th, unsigned short* __restrict__ W2Tl) {
  const int n = blockIdx.x, t = threadIdx.x;
  if (t < KC1) {
    float v = (t < 67) ? W1[(size_t)t * HH + n] : 0.0f;
    unsigned int h, l; split2(v, h, l);
    W1Th[n * KC1 + t] = (unsigned short)h;
    W1Tl[n * KC1 + t] = (unsigned short)l;
  }
  {
    float v = W2[(size_t)t * HH + n];
    unsigned int h, l; split2(v, h, l);
    W2Th[n * HH + t] = (unsigned short)h;
    W2Tl[n * HH + t] = (unsigned short)l;
  }
}

// ---------------------------------------------------------------------------
// init: zero progress[16] + claim (d_ws is 0xAA-poisoned before every launch)
// ---------------------------------------------------------------------------
__global__ void init_kernel(unsigned int* progress, unsigned int* claim) {
  int t = threadIdx.x;
  if (t < NPROD) progress[t] = 0u;
  if (t == NPROD) *claim = 0u;
}

// ---------------------------------------------------------------------------
// FUSED producer-consumer kernel, R13. 256 blocks x 512 threads, 82KB LDS ->
// exactly 1 block/CU (2x82 > 160KB), grid == CU count -> co-residency
// guaranteed; producers own their CU EXCLUSIVELY (R12 lesson: a co-resident
// consumer block slows the FPS critical chain and the pipeline is
// production-paced). Blocks 0..15: R7-exact FPS on threads 0..255 (threads
// 256+ exit; AMD s_barrier counts live waves only). Blocks 16..255: DUAL
// consumer pipelines — halves h=0,1 (4 waves + 41KB LDS region each) claim
// centers i0, i0+1 and run ballq+mlp in lockstep (block barriers), doubling
// per-CU service throughput: capacity ~31 centers/us > production ~26.6/us
// -> production-bound. All numerics bit-identical to R11/R12 (passed,
// absmax 0.015625).
// ---------------------------------------------------------------------------
__global__ __launch_bounds__(512, 2) void fused_kernel(
    const float* __restrict__ pos, const float* __restrict__ x,
    const float* __restrict__ pn,
    float* __restrict__ pos_s_ws, float* __restrict__ pos_s_out,
    const unsigned short* __restrict__ W1Th, const unsigned short* __restrict__ W1Tl,
    const unsigned short* __restrict__ W2Th, const unsigned short* __restrict__ W2Tl,
    const float* __restrict__ b1, const float* __restrict__ b2,
    float* __restrict__ out,
    unsigned int* __restrict__ progress, unsigned int* __restrict__ claim) {
#pragma clang fp contract(off)
  __shared__ __attribute__((aligned(16))) unsigned char LBUF[83968];
  const int t = threadIdx.x;
  const int lane = t & 63;

  if (blockIdx.x < NPROD) {
    // =================== PRODUCER: FPS for batch b ===================
    if (t >= FTH) return;            // waves 4..7 exit; barrier counts live waves
    __builtin_amdgcn_s_setprio(3);
    const int wv = t >> 6;           // 0..3
    const int b = blockIdx.x;
    float4* P4 = (float4*)LBUF;                          // 65536 B
    float* SXa = (float*)(LBUF + 65536);                 // 4096 B
    float* SYa = (float*)(LBUF + 69632);                 // 4096 B
    float* SZa = (float*)(LBUF + 73728);                 // 4096 B
    unsigned long long* cand = (unsigned long long*)(LBUF + 77824); // [2][4]
    const float* pb = pos + (size_t)b * NN * 3;
    float px[FPT], py[FPT], pz[FPT], dd[FPT];
#pragma unroll
    for (int j = 0; j < FPT; ++j) {
      int i = t + j * FTH;
      float xx = pb[i * 3 + 0], yy = pb[i * 3 + 1], zz = pb[i * 3 + 2];
      P4[i] = make_float4(xx, yy, zz, 0.0f);
      px[j] = xx; py[j] = yy; pz[j] = zz;
      dd[j] = 3.4028234663852886e38f;
    }
    __syncthreads();
    float4 c4 = P4[0];
    float sx = c4.x, sy = c4.y, sz = c4.z;
    if (t == 0) { SXa[0] = sx; SYa[0] = sy; SZa[0] = sz; }

    for (int m = 1; m < MM; ++m) {
      float bv = -1.0f;
      int   bi = 0;
#pragma unroll
      for (int j = 0; j < FPT; ++j) {
        float dx = px[j] - sx, dy = py[j] - sy, dz = pz[j] - sz;
        float d2 = (dx * dx + dy * dy) + dz * dz;   // no FMA (pragma)
        float nd = fminf(dd[j], d2);
        dd[j] = nd;
        if (nd > bv) { bv = nd; bi = t + (j << 8); }
      }
      unsigned int kh = __float_as_uint(bv);
      unsigned int kl = ~(unsigned int)bi;
      dpp_max64<0x111, 0xf>(kh, kl);
      dpp_max64<0x112, 0xf>(kh, kl);
      dpp_max64<0x114, 0xf>(kh, kl);
      dpp_max64<0x118, 0xf>(kh, kl);
      dpp_max64<0x142, 0xa>(kh, kl);
      dpp_max64<0x143, 0xc>(kh, kl);
      if (lane == 63)
        cand[(m & 1) * 4 + wv] = ((unsigned long long)kh << 32) | kl;
      __syncthreads();
      unsigned long long best = cand[(m & 1) * 4 + 0];
#pragma unroll
      for (int w = 1; w < 4; ++w) {
        unsigned long long ok = cand[(m & 1) * 4 + w];
        best = ok > best ? ok : best;
      }
      int fi = (int)(~(unsigned int)(best & 0xffffffffull));
      float4 w4 = P4[fi];
      sx = w4.x; sy = w4.y; sz = w4.z;
      if (t == 0) {
        SXa[m] = sx; SYa[m] = sy; SZa[m] = sz;
        if ((m & 7) == 7) {
          int base = m - 7;
          for (int j = 0; j < 8; ++j) {
            size_t o = ((size_t)b * MM + base + j) * 3;
            float ox = SXa[base + j], oy = SYa[base + j], oz = SZa[base + j];
            __hip_atomic_store(&pos_s_ws[o + 0], ox, __ATOMIC_RELAXED, __HIP_MEMORY_SCOPE_AGENT);
            __hip_atomic_store(&pos_s_ws[o + 1], oy, __ATOMIC_RELAXED, __HIP_MEMORY_SCOPE_AGENT);
            __hip_atomic_store(&pos_s_ws[o + 2], oz, __ATOMIC_RELAXED, __HIP_MEMORY_SCOPE_AGENT);
            pos_s_out[o + 0] = ox; pos_s_out[o + 1] = oy; pos_s_out[o + 2] = oz;
          }
          __hip_atomic_store(&progress[b], (unsigned int)(m + 1),
                             __ATOMIC_RELEASE, __HIP_MEMORY_SCOPE_AGENT);
        }
      }
    }
    return;
  }

  // ============ CONSUMER: two 4-wave pipelines (halves h=0,1) ============
  const int h = t >> 8;            // half id
  const int th = t & 255;          // half-local thread id
  const int wvh = (t >> 6) & 3;    // half-local wave id
  unsigned char* HB = LBUF + h * HSTRIDE;
  unsigned short* Ah = (unsigned short*)HB;
  unsigned short* Al = (unsigned short*)(HB + 64 * SA * 2);
  unsigned short* Hh = (unsigned short*)HB;
  unsigned short* Hl = (unsigned short*)(HB + 64 * SH * 2);
  int* nbr_s = (int*)(HB + 34816);
  unsigned long long* masksL = (unsigned long long*)(HB + 35072);
  int* prefixL = (int*)(HB + 35584);
  float* ctr = (float*)(HB + 35840);
  int* cntS = (int*)(HB + 35856);
  volatile int* cidShare = (int*)(LBUF + 83960);   // block-wide
  const int r = lane & 15, q = lane >> 4;
  const int wbase = wvh * 32;

  while (true) {
    if (t == 0) {
      unsigned int i = __hip_atomic_fetch_add(claim, 2u, __ATOMIC_RELAXED,
                                              __HIP_MEMORY_SCOPE_AGENT);
      *cidShare = (int)i;
    }
    __syncthreads();
    int i0 = *cidShare;
    if (i0 >= BB * MM) break;                      // uniform exit
    const int i = i0 + h;
    const bool active = (i < BB * MM);
    const int cid = active ? (((i & 15) << 10) | (i >> 4)) : 0;
    const int b = cid >> 10;
    const int m = cid & 1023;

    if (active && th < 64) {   // half's wave 0 polls production progress
      while ((int)__hip_atomic_load(&progress[b], __ATOMIC_RELAXED,
                                    __HIP_MEMORY_SCOPE_AGENT) <= m)
        __builtin_amdgcn_s_sleep(32);
    }
    if (active && th < 3)
      ctr[th] = __hip_atomic_load(&pos_s_ws[(size_t)cid * 3 + th],
                                  __ATOMIC_RELAXED, __HIP_MEMORY_SCOPE_AGENT);
    __syncthreads();

    // ---- ballq: 4-wave mask pass + prefix + compaction (per half) ----
    const float sx = ctr[0], sy = ctr[1], sz = ctr[2];
    const float sn = (sx * sx + sy * sy) + sz * sz;
    const float* pb = pos + (size_t)b * NN * 3;
    const float* pnb = pn + (size_t)b * NN;
    if (active) {
#pragma unroll
      for (int cc = 0; cc < 16; ++cc) {
        int c = (wvh << 4) + cc;
        int n = (c << 6) + lane;
        float xx = pb[n * 3 + 0], yy = pb[n * 3 + 1], zz = pb[n * 3 + 2];
        float dot = __builtin_fmaf(sz, zz, __builtin_fmaf(sy, yy, sx * xx));
        float d2 = (sn + pnb[n]) - 2.0f * dot;
        bool pred = d2 <= 0.04f;
        unsigned long long mask = __ballot(pred);
        if (lane == 0) masksL[c] = mask;
      }
    }
    __syncthreads();
    if (active && th < 64) {
      int pc = (int)__popcll(masksL[lane]);
      int incl = pc;
#pragma unroll
      for (int off = 1; off < 64; off <<= 1) {
        int o2 = __shfl_up(incl, off, 64);
        if (lane >= off) incl += o2;
      }
      prefixL[lane] = incl - pc;
      if (lane == 63) *cntS = incl < KK ? incl : KK;
    }
    __syncthreads();
    const int cnt = *cntS;
    if (active) {
#pragma unroll
      for (int cc = 0; cc < 16; ++cc) {
        int c = (wvh << 4) + cc;
        unsigned long long mk = masksL[c];
        bool pred = (mk >> lane) & 1ull;
        int slot = prefixL[c] + (int)__popcll(mk & ((1ull << lane) - 1ull));
        if (pred && slot < KK) nbr_s[slot] = (c << 6) + lane;
      }
    }
    __syncthreads();

    // ---- gather + hi/lo split into LDS feat planes ----
    if (active) {
      const int kn = th >> 2, p = th & 3;
      float vals[16];
      float d0 = 0.0f, d1 = 0.0f, d2v = 0.0f;
      if (kn < cnt) {
        int n = nbr_s[kn];
        const float* xp = x + ((size_t)b * NN + n) * CC + p * 16;
#pragma unroll
        for (int ii = 0; ii < 4; ++ii) {
          float4 v = ((const float4*)xp)[ii];
          vals[ii * 4 + 0] = v.x; vals[ii * 4 + 1] = v.y;
          vals[ii * 4 + 2] = v.z; vals[ii * 4 + 3] = v.w;
        }
        if (p == 0) {
          const float* pp = pos + ((size_t)b * NN + n) * 3;
          d0 = pp[0] - sx; d1 = pp[1] - sy; d2v = pp[2] - sz;
        }
      } else {
#pragma unroll
        for (int ii = 0; ii < 16; ++ii) vals[ii] = 0.0f;
      }
#pragma unroll
      for (int j = 0; j < 16; j += 2) {
        unsigned int h0, l0, h1, l1;
        split2(vals[j], h0, l0);
        split2(vals[j + 1], h1, l1);
        int c = p * 16 + j;
        *(unsigned int*)&Ah[kn * SA + c] = h0 | (h1 << 16);
        *(unsigned int*)&Al[kn * SA + c] = l0 | (l1 << 16);
      }
      if (p == 0) {
        unsigned int h0, l0, h1, l1, h2, l2;
        split2(d0, h0, l0); split2(d1, h1, l1); split2(d2v, h2, l2);
        *(unsigned int*)&Ah[kn * SA + 64] = h0 | (h1 << 16);
        *(unsigned int*)&Al[kn * SA + 64] = l0 | (l1 << 16);
        *(unsigned int*)&Ah[kn * SA + 66] = h2;
        *(unsigned int*)&Al[kn * SA + 66] = l2;
      } else if (p == 1) {
#pragma unroll
        for (int c = 68; c < 80; c += 2) {
          *(unsigned int*)&Ah[kn * SA + c] = 0u;
          *(unsigned int*)&Al[kn * SA + c] = 0u;
        }
      } else if (p == 2) {
#pragma unroll
        for (int c = 80; c < 96; c += 2) {
          *(unsigned int*)&Ah[kn * SA + c] = 0u;
          *(unsigned int*)&Al[kn * SA + c] = 0u;
        }
      }
    }
    __syncthreads();

    f32x4 acc[4][2];
#pragma unroll
    for (int mt = 0; mt < 4; ++mt)
#pragma unroll
      for (int nt = 0; nt < 2; ++nt) acc[mt][nt] = (f32x4)0.0f;

    // ---- layer 1 ----
    if (active) {
#pragma unroll
      for (int kc = 0; kc < 3; ++kc) {
        bf16x8 bh[2], bl[2];
#pragma unroll
        for (int nt = 0; nt < 2; ++nt) {
          int o = (wbase + nt * 16 + r) * KC1 + kc * 32 + q * 8;
          bh[nt] = *(const bf16x8*)(W1Th + o);
          bl[nt] = *(const bf16x8*)(W1Tl + o);
        }
#pragma unroll
        for (int mt = 0; mt < 4; ++mt) {
          int o = (mt * 16 + r) * SA + kc * 32 + q * 8;
          bf16x8 ah = *(const bf16x8*)&Ah[o];
          bf16x8 al = *(const bf16x8*)&Al[o];
#pragma unroll
          for (int nt = 0; nt < 2; ++nt) {
            acc[mt][nt] = __builtin_amdgcn_mfma_f32_16x16x32_bf16(ah, bh[nt], acc[mt][nt], 0, 0, 0);
            acc[mt][nt] = __builtin_amdgcn_mfma_f32_16x16x32_bf16(al, bh[nt], acc[mt][nt], 0, 0, 0);
            acc[mt][nt] = __builtin_amdgcn_mfma_f32_16x16x32_bf16(ah, bl[nt], acc[mt][nt], 0, 0, 0);
          }
        }
      }
    }
    __syncthreads();   // alias guard: A-plane reads done before H overwrite

    if (active) {
      float b1v[2] = { b1[wbase + r], b1[wbase + 16 + r] };
#pragma unroll
      for (int mt = 0; mt < 4; ++mt)
#pragma unroll
        for (int nt = 0; nt < 2; ++nt)
#pragma unroll
          for (int ii = 0; ii < 4; ++ii) {
            int mm = mt * 16 + q * 4 + ii;
            int n = wbase + nt * 16 + r;
            float v = fmaxf(acc[mt][nt][ii] + b1v[nt], 0.0f);
            unsigned int hh2, ll2; split2(v, hh2, ll2);
            Hh[mm * SH + n] = (unsigned short)hh2;
            Hl[mm * SH + n] = (unsigned short)ll2;
          }
    }
    __syncthreads();

    // ---- layer 2 + masked max ----
#pragma unroll
    for (int mt = 0; mt < 4; ++mt)
#pragma unroll
      for (int nt = 0; nt < 2; ++nt) acc[mt][nt] = (f32x4)0.0f;
    if (active) {
#pragma unroll
      for (int kc = 0; kc < 4; ++kc) {
        bf16x8 bh[2], bl[2];
#pragma unroll
        for (int nt = 0; nt < 2; ++nt) {
          int o = (wbase + nt * 16 + r) * HH + kc * 32 + q * 8;
          bh[nt] = *(const bf16x8*)(W2Th + o);
          bl[nt] = *(const bf16x8*)(W2Tl + o);
        }
#pragma unroll
        for (int mt = 0; mt < 4; ++mt) {
          int o = (mt * 16 + r) * SH + kc * 32 + q * 8;
          bf16x8 ah = *(const bf16x8*)&Hh[o];
          bf16x8 al = *(const bf16x8*)&Hl[o];
#pragma unroll
          for (int nt = 0; nt < 2; ++nt) {
            acc[mt][nt] = __builtin_amdgcn_mfma_f32_16x16x32_bf16(ah, bh[nt], acc[mt][nt], 0, 0, 0);
            acc[mt][nt] = __builtin_amdgcn_mfma_f32_16x16x32_bf16(al, bh[nt], acc[mt][nt], 0, 0, 0);
            acc[mt][nt] = __builtin_amdgcn_mfma_f32_16x16x32_bf16(ah, bl[nt], acc[mt][nt], 0, 0, 0);
          }
        }
      }
      float b2v[2] = { b2[wbase + r], b2[wbase + 16 + r] };
#pragma unroll
      for (int nt = 0; nt < 2; ++nt) {
        float vmax = NEGV;
#pragma unroll
        for (int mt = 0; mt < 4; ++mt)
#pragma unroll
          for (int ii = 0; ii < 4; ++ii) {
            int mm = mt * 16 + q * 4 + ii;
            float v = fmaxf(acc[mt][nt][ii] + b2v[nt], 0.0f);
            if (mm < cnt) vmax = fmaxf(vmax, v);
          }
        vmax = fmaxf(vmax, __shfl_xor(vmax, 16, 64));
        vmax = fmaxf(vmax, __shfl_xor(vmax, 32, 64));
        if (q == 0)
          out[(size_t)cid * HH + wbase + nt * 16 + r] = (cnt > 0) ? vmax : 0.0f;
      }
    }
    __syncthreads();   // LDS reuse guard before next center
  }
}

// ---------------------------------------------------------------------------
extern "C" void kernel_launch(void* const* d_in, const int* in_sizes, int n_in,
                              void* d_out, int out_size, void* d_ws, size_t ws_size,
                              hipStream_t stream) {
  const float* x   = (const float*)d_in[0];
  const float* pos = (const float*)d_in[1];
  const float* W1  = (const float*)d_in[2];
  const float* b1  = (const float*)d_in[3];
  const float* W2  = (const float*)d_in[4];
  const float* b2  = (const float*)d_in[5];
  float* out = (float*)d_out;
  float* pos_s_out = out + (size_t)BB * MM * HH;

  char* ws = (char*)d_ws;
  float* pos_s_ws = (float*)(ws);                          // 196608 B
  float* pn       = (float*)(ws + 196608);                 // 262144 B
  unsigned short* W1Th = (unsigned short*)(ws + 458752);   // 24576 B
  unsigned short* W1Tl = (unsigned short*)(ws + 483328);   // 24576 B
  unsigned short* W2Th = (unsigned short*)(ws + 507904);   // 32768 B
  unsigned short* W2Tl = (unsigned short*)(ws + 540672);   // 32768 B
  unsigned int* progress = (unsigned int*)(ws + 573440);   // 64 B
  unsigned int* claim    = (unsigned int*)(ws + 573504);   // 4 B

  wprep_kernel<<<HH, 128, 0, stream>>>(W1, W2, W1Th, W1Tl, W2Th, W2Tl);
  pn_kernel<<<(BB * NN) / 256, 256, 0, stream>>>(pos, pn);
  init_kernel<<<1, 64, 0, stream>>>(progress, claim);
  fused_kernel<<<GTOT, 512, 0, stream>>>(pos, x, pn, pos_s_ws, pos_s_out,
                                         W1Th, W1Tl, W2Th, W2Tl, b1, b2, out,
                                         progress, claim);
}

// Round 14
// 821.586 us; speedup vs baseline: 1.3149x; 1.0870x over previous
//
#include <hip/hip_runtime.h>
#include <cstdint>
#include <cstddef>

#define BB 16
#define NN 4096
#define CC 64
#define MM 1024
#define KK 64
#define HH 128
#define NEGV -1.0e30f

#define FTH 256   // fps active threads (4 waves)
#define FPT 16    // fps points per thread (FTH*FPT == NN)
#define NPROD 16  // producer blocks (one per batch)
#define GTOT 256  // total blocks: 1 per CU exactly (82KB LDS forces it)
#define PSTRIDE 32  // progress counter stride in u32 (128B: one cacheline/batch)

#define KC1 96    // layer-1 K dim padded (67 -> 96)
#define SA 104    // LDS stride of feat planes
#define SH 136    // LDS stride of h1 planes
#define HSTRIDE 41984  // per-half consumer LDS region

typedef __attribute__((ext_vector_type(8))) short bf16x8;
typedef __attribute__((ext_vector_type(4))) float f32x4;

__device__ __forceinline__ unsigned int f2bf(float f) {
  unsigned int u = __float_as_uint(f);
  return (u + 0x7fffu + ((u >> 16) & 1u)) >> 16;
}
__device__ __forceinline__ void split2(float f, unsigned int& h, unsigned int& l) {
  h = f2bf(f);
  float hf = __uint_as_float(h << 16);
  l = f2bf(f - hf);
}

template <int CTRL, int RM>
__device__ __forceinline__ void dpp_max64(unsigned int& hi, unsigned int& lo) {
  unsigned int shi = (unsigned int)__builtin_amdgcn_update_dpp(
      (int)hi, (int)hi, CTRL, RM, 0xf, false);
  unsigned int slo = (unsigned int)__builtin_amdgcn_update_dpp(
      (int)lo, (int)lo, CTRL, RM, 0xf, false);
  unsigned long long cur = ((unsigned long long)hi << 32) | lo;
  unsigned long long oth = ((unsigned long long)shi << 32) | slo;
  if (oth > cur) { hi = shi; lo = slo; }
}

// ---------------------------------------------------------------------------
// pn: |p|^2 per point, exact order (x^2+y^2)+z^2, no FMA.
// ---------------------------------------------------------------------------
__global__ __launch_bounds__(256) void pn_kernel(const float* __restrict__ pos,
                                                 float* __restrict__ pn) {
#pragma clang fp contract(off)
  int i = blockIdx.x * 256 + threadIdx.x;
  if (i < BB * NN) {
    float x = pos[(size_t)i * 3 + 0];
    float y = pos[(size_t)i * 3 + 1];
    float z = pos[(size_t)i * 3 + 2];
    pn[i] = (x * x + y * y) + z * z;
  }
}

// ---------------------------------------------------------------------------
// Weight prep: transpose + pad + bf16 hi/lo split, B-fragment layout [n][k].
// ---------------------------------------------------------------------------
__global__ __launch_bounds__(128) void wprep_kernel(
    const float* __restrict__ W1, const float* __restrict__ W2,
    unsigned short* __restrict__ W1Th, unsigned short* __restrict__ W1Tl,
    unsigned short* __restrict__ W2Th, unsigned short* __restrict__ W2Tl) {
  const int n = blockIdx.x, t = threadIdx.x;
  if (t < KC1) {
    float v = (t < 67) ? W1[(size_t)t * HH + n] : 0.0f;
    unsigned int h, l; split2(v, h, l);
    W1Th[n * KC1 + t] = (unsigned short)h;
    W1Tl[n * KC1 + t] = (unsigned short)l;
  }
  {
    float v = W2[(size_t)t * HH + n];
    unsigned int h, l; split2(v, h, l);
    W2Th[n * HH + t] = (unsigned short)h;
    W2Tl[n * HH + t] = (unsigned short)l;
  }
}

// ---------------------------------------------------------------------------
// init: zero padded progress[16*32] + claim (ws is 0xAA-poisoned per launch)
// ---------------------------------------------------------------------------
__global__ void init_kernel(unsigned int* progress, unsigned int* claim) {
  int t = threadIdx.x;
  if (t < NPROD * PSTRIDE) progress[t] = 0u;
  if (t == NPROD * PSTRIDE) *claim = 0u;
}

// ---------------------------------------------------------------------------
// FUSED producer-consumer kernel, R14. 256 blocks x 512 threads, 82KB LDS ->
// 1 block/CU, grid == CU count -> co-resident; producers own their CU
// exclusively. R14 contention diet vs R13 (which ran production ~35% slower
// than standalone FPS): (1) progress counters padded to one 128B line per
// batch (R13 had all 16 in ONE line polled by ~480 pipelines -> ping-pong on
// every RELEASE); (2) flush every 16 iters (64 vmcnt-drains vs 128 — the
// compiler drains vmcnt(0) before each post-flush s_barrier); (3) pos_s_out
// bulk-written after the FPS loop (24 fewer in-loop stores per flush);
// (4) consumer poll sleep 32->64. All numerics bit-identical (R13 passed,
// absmax 0.015625).
// ---------------------------------------------------------------------------
__global__ __launch_bounds__(512, 2) void fused_kernel(
    const float* __restrict__ pos, const float* __restrict__ x,
    const float* __restrict__ pn,
    float* __restrict__ pos_s_ws, float* __restrict__ pos_s_out,
    const unsigned short* __restrict__ W1Th, const unsigned short* __restrict__ W1Tl,
    const unsigned short* __restrict__ W2Th, const unsigned short* __restrict__ W2Tl,
    const float* __restrict__ b1, const float* __restrict__ b2,
    float* __restrict__ out,
    unsigned int* __restrict__ progress, unsigned int* __restrict__ claim) {
#pragma clang fp contract(off)
  __shared__ __attribute__((aligned(16))) unsigned char LBUF[83968];
  const int t = threadIdx.x;
  const int lane = t & 63;

  if (blockIdx.x < NPROD) {
    // =================== PRODUCER: FPS for batch b ===================
    if (t >= FTH) return;            // waves 4..7 exit; barrier counts live waves
    __builtin_amdgcn_s_setprio(3);
    const int wv = t >> 6;           // 0..3
    const int b = blockIdx.x;
    float4* P4 = (float4*)LBUF;                          // 65536 B
    float* SXa = (float*)(LBUF + 65536);                 // 4096 B
    float* SYa = (float*)(LBUF + 69632);                 // 4096 B
    float* SZa = (float*)(LBUF + 73728);                 // 4096 B
    unsigned long long* cand = (unsigned long long*)(LBUF + 77824); // [2][4]
    const float* pb = pos + (size_t)b * NN * 3;
    float px[FPT], py[FPT], pz[FPT], dd[FPT];
#pragma unroll
    for (int j = 0; j < FPT; ++j) {
      int i = t + j * FTH;
      float xx = pb[i * 3 + 0], yy = pb[i * 3 + 1], zz = pb[i * 3 + 2];
      P4[i] = make_float4(xx, yy, zz, 0.0f);
      px[j] = xx; py[j] = yy; pz[j] = zz;
      dd[j] = 3.4028234663852886e38f;
    }
    __syncthreads();
    float4 c4 = P4[0];
    float sx = c4.x, sy = c4.y, sz = c4.z;
    if (t == 0) { SXa[0] = sx; SYa[0] = sy; SZa[0] = sz; }

    for (int m = 1; m < MM; ++m) {
      float bv = -1.0f;
      int   bi = 0;
#pragma unroll
      for (int j = 0; j < FPT; ++j) {
        float dx = px[j] - sx, dy = py[j] - sy, dz = pz[j] - sz;
        float d2 = (dx * dx + dy * dy) + dz * dz;   // no FMA (pragma)
        float nd = fminf(dd[j], d2);
        dd[j] = nd;
        if (nd > bv) { bv = nd; bi = t + (j << 8); }
      }
      unsigned int kh = __float_as_uint(bv);
      unsigned int kl = ~(unsigned int)bi;
      dpp_max64<0x111, 0xf>(kh, kl);
      dpp_max64<0x112, 0xf>(kh, kl);
      dpp_max64<0x114, 0xf>(kh, kl);
      dpp_max64<0x118, 0xf>(kh, kl);
      dpp_max64<0x142, 0xa>(kh, kl);
      dpp_max64<0x143, 0xc>(kh, kl);
      if (lane == 63)
        cand[(m & 1) * 4 + wv] = ((unsigned long long)kh << 32) | kl;
      __syncthreads();
      unsigned long long best = cand[(m & 1) * 4 + 0];
#pragma unroll
      for (int w = 1; w < 4; ++w) {
        unsigned long long ok = cand[(m & 1) * 4 + w];
        best = ok > best ? ok : best;
      }
      int fi = (int)(~(unsigned int)(best & 0xffffffffull));
      float4 w4 = P4[fi];
      sx = w4.x; sy = w4.y; sz = w4.z;
      if (t == 0) {
        SXa[m] = sx; SYa[m] = sy; SZa[m] = sz;
        if ((m & 15) == 15) {
          int base = m - 15;
          for (int j = 0; j < 16; ++j) {
            size_t o = ((size_t)b * MM + base + j) * 3;
            __hip_atomic_store(&pos_s_ws[o + 0], SXa[base + j], __ATOMIC_RELAXED, __HIP_MEMORY_SCOPE_AGENT);
            __hip_atomic_store(&pos_s_ws[o + 1], SYa[base + j], __ATOMIC_RELAXED, __HIP_MEMORY_SCOPE_AGENT);
            __hip_atomic_store(&pos_s_ws[o + 2], SZa[base + j], __ATOMIC_RELAXED, __HIP_MEMORY_SCOPE_AGENT);
          }
          __hip_atomic_store(&progress[b * PSTRIDE], (unsigned int)(m + 1),
                             __ATOMIC_RELEASE, __HIP_MEMORY_SCOPE_AGENT);
        }
      }
    }
    __syncthreads();   // SXa/SYa/SZa final values visible to all threads
    for (int i = t; i < MM; i += FTH) {
      size_t o = ((size_t)b * MM + i) * 3;
      pos_s_out[o + 0] = SXa[i];
      pos_s_out[o + 1] = SYa[i];
      pos_s_out[o + 2] = SZa[i];
    }
    return;
  }

  // ============ CONSUMER: two 4-wave pipelines (halves h=0,1) ============
  const int h = t >> 8;            // half id
  const int th = t & 255;          // half-local thread id
  const int wvh = (t >> 6) & 3;    // half-local wave id
  unsigned char* HB = LBUF + h * HSTRIDE;
  unsigned short* Ah = (unsigned short*)HB;
  unsigned short* Al = (unsigned short*)(HB + 64 * SA * 2);
  unsigned short* Hh = (unsigned short*)HB;
  unsigned short* Hl = (unsigned short*)(HB + 64 * SH * 2);
  int* nbr_s = (int*)(HB + 34816);
  unsigned long long* masksL = (unsigned long long*)(HB + 35072);
  int* prefixL = (int*)(HB + 35584);
  float* ctr = (float*)(HB + 35840);
  int* cntS = (int*)(HB + 35856);
  volatile int* cidShare = (int*)(LBUF + 83960);   // block-wide
  const int r = lane & 15, q = lane >> 4;
  const int wbase = wvh * 32;

  while (true) {
    if (t == 0) {
      unsigned int i = __hip_atomic_fetch_add(claim, 2u, __ATOMIC_RELAXED,
                                              __HIP_MEMORY_SCOPE_AGENT);
      *cidShare = (int)i;
    }
    __syncthreads();
    int i0 = *cidShare;
    if (i0 >= BB * MM) break;                      // uniform exit
    const int i = i0 + h;
    const bool active = (i < BB * MM);
    const int cid = active ? (((i & 15) << 10) | (i >> 4)) : 0;
    const int b = cid >> 10;
    const int m = cid & 1023;

    if (active && th < 64) {   // half's wave 0 polls production progress
      while ((int)__hip_atomic_load(&progress[b * PSTRIDE], __ATOMIC_RELAXED,
                                    __HIP_MEMORY_SCOPE_AGENT) <= m)
        __builtin_amdgcn_s_sleep(64);
    }
    if (active && th < 3)
      ctr[th] = __hip_atomic_load(&pos_s_ws[(size_t)cid * 3 + th],
                                  __ATOMIC_RELAXED, __HIP_MEMORY_SCOPE_AGENT);
    __syncthreads();

    // ---- ballq: 4-wave mask pass + prefix + compaction (per half) ----
    const float sx = ctr[0], sy = ctr[1], sz = ctr[2];
    const float sn = (sx * sx + sy * sy) + sz * sz;
    const float* pb = pos + (size_t)b * NN * 3;
    const float* pnb = pn + (size_t)b * NN;
    if (active) {
#pragma unroll
      for (int cc = 0; cc < 16; ++cc) {
        int c = (wvh << 4) + cc;
        int n = (c << 6) + lane;
        float xx = pb[n * 3 + 0], yy = pb[n * 3 + 1], zz = pb[n * 3 + 2];
        float dot = __builtin_fmaf(sz, zz, __builtin_fmaf(sy, yy, sx * xx));
        float d2 = (sn + pnb[n]) - 2.0f * dot;
        bool pred = d2 <= 0.04f;
        unsigned long long mask = __ballot(pred);
        if (lane == 0) masksL[c] = mask;
      }
    }
    __syncthreads();
    if (active && th < 64) {
      int pc = (int)__popcll(masksL[lane]);
      int incl = pc;
#pragma unroll
      for (int off = 1; off < 64; off <<= 1) {
        int o2 = __shfl_up(incl, off, 64);
        if (lane >= off) incl += o2;
      }
      prefixL[lane] = incl - pc;
      if (lane == 63) *cntS = incl < KK ? incl : KK;
    }
    __syncthreads();
    const int cnt = *cntS;
    if (active) {
#pragma unroll
      for (int cc = 0; cc < 16; ++cc) {
        int c = (wvh << 4) + cc;
        unsigned long long mk = masksL[c];
        bool pred = (mk >> lane) & 1ull;
        int slot = prefixL[c] + (int)__popcll(mk & ((1ull << lane) - 1ull));
        if (pred && slot < KK) nbr_s[slot] = (c << 6) + lane;
      }
    }
    __syncthreads();

    // ---- gather + hi/lo split into LDS feat planes ----
    if (active) {
      const int kn = th >> 2, p = th & 3;
      float vals[16];
      float d0 = 0.0f, d1 = 0.0f, d2v = 0.0f;
      if (kn < cnt) {
        int n = nbr_s[kn];
        const float* xp = x + ((size_t)b * NN + n) * CC + p * 16;
#pragma unroll
        for (int ii = 0; ii < 4; ++ii) {
          float4 v = ((const float4*)xp)[ii];
          vals[ii * 4 + 0] = v.x; vals[ii * 4 + 1] = v.y;
          vals[ii * 4 + 2] = v.z; vals[ii * 4 + 3] = v.w;
        }
        if (p == 0) {
          const float* pp = pos + ((size_t)b * NN + n) * 3;
          d0 = pp[0] - sx; d1 = pp[1] - sy; d2v = pp[2] - sz;
        }
      } else {
#pragma unroll
        for (int ii = 0; ii < 16; ++ii) vals[ii] = 0.0f;
      }
#pragma unroll
      for (int j = 0; j < 16; j += 2) {
        unsigned int h0, l0, h1, l1;
        split2(vals[j], h0, l0);
        split2(vals[j + 1], h1, l1);
        int c = p * 16 + j;
        *(unsigned int*)&Ah[kn * SA + c] = h0 | (h1 << 16);
        *(unsigned int*)&Al[kn * SA + c] = l0 | (l1 << 16);
      }
      if (p == 0) {
        unsigned int h0, l0, h1, l1, h2, l2;
        split2(d0, h0, l0); split2(d1, h1, l1); split2(d2v, h2, l2);
        *(unsigned int*)&Ah[kn * SA + 64] = h0 | (h1 << 16);
        *(unsigned int*)&Al[kn * SA + 64] = l0 | (l1 << 16);
        *(unsigned int*)&Ah[kn * SA + 66] = h2;
        *(unsigned int*)&Al[kn * SA + 66] = l2;
      } else if (p == 1) {
#pragma unroll
        for (int c = 68; c < 80; c += 2) {
          *(unsigned int*)&Ah[kn * SA + c] = 0u;
          *(unsigned int*)&Al[kn * SA + c] = 0u;
        }
      } else if (p == 2) {
#pragma unroll
        for (int c = 80; c < 96; c += 2) {
          *(unsigned int*)&Ah[kn * SA + c] = 0u;
          *(unsigned int*)&Al[kn * SA + c] = 0u;
        }
      }
    }
    __syncthreads();

    f32x4 acc[4][2];
#pragma unroll
    for (int mt = 0; mt < 4; ++mt)
#pragma unroll
      for (int nt = 0; nt < 2; ++nt) acc[mt][nt] = (f32x4)0.0f;

    // ---- layer 1 ----
    if (active) {
#pragma unroll
      for (int kc = 0; kc < 3; ++kc) {
        bf16x8 bh[2], bl[2];
#pragma unroll
        for (int nt = 0; nt < 2; ++nt) {
          int o = (wbase + nt * 16 + r) * KC1 + kc * 32 + q * 8;
          bh[nt] = *(const bf16x8*)(W1Th + o);
          bl[nt] = *(const bf16x8*)(W1Tl + o);
        }
#pragma unroll
        for (int mt = 0; mt < 4; ++mt) {
          int o = (mt * 16 + r) * SA + kc * 32 + q * 8;
          bf16x8 ah = *(const bf16x8*)&Ah[o];
          bf16x8 al = *(const bf16x8*)&Al[o];
#pragma unroll
          for (int nt = 0; nt < 2; ++nt) {
            acc[mt][nt] = __builtin_amdgcn_mfma_f32_16x16x32_bf16(ah, bh[nt], acc[mt][nt], 0, 0, 0);
            acc[mt][nt] = __builtin_amdgcn_mfma_f32_16x16x32_bf16(al, bh[nt], acc[mt][nt], 0, 0, 0);
            acc[mt][nt] = __builtin_amdgcn_mfma_f32_16x16x32_bf16(ah, bl[nt], acc[mt][nt], 0, 0, 0);
          }
        }
      }
    }
    __syncthreads();   // alias guard: A-plane reads done before H overwrite

    if (active) {
      float b1v[2] = { b1[wbase + r], b1[wbase + 16 + r] };
#pragma unroll
      for (int mt = 0; mt < 4; ++mt)
#pragma unroll
        for (int nt = 0; nt < 2; ++nt)
#pragma unroll
          for (int ii = 0; ii < 4; ++ii) {
            int mm = mt * 16 + q * 4 + ii;
            int n = wbase + nt * 16 + r;
            float v = fmaxf(acc[mt][nt][ii] + b1v[nt], 0.0f);
            unsigned int hh2, ll2; split2(v, hh2, ll2);
            Hh[mm * SH + n] = (unsigned short)hh2;
            Hl[mm * SH + n] = (unsigned short)ll2;
          }
    }
    __syncthreads();

    // ---- layer 2 + masked max ----
#pragma unroll
    for (int mt = 0; mt < 4; ++mt)
#pragma unroll
      for (int nt = 0; nt < 2; ++nt) acc[mt][nt] = (f32x4)0.0f;
    if (active) {
#pragma unroll
      for (int kc = 0; kc < 4; ++kc) {
        bf16x8 bh[2], bl[2];
#pragma unroll
        for (int nt = 0; nt < 2; ++nt) {
          int o = (wbase + nt * 16 + r) * HH + kc * 32 + q * 8;
          bh[nt] = *(const bf16x8*)(W2Th + o);
          bl[nt] = *(const bf16x8*)(W2Tl + o);
        }
#pragma unroll
        for (int mt = 0; mt < 4; ++mt) {
          int o = (mt * 16 + r) * SH + kc * 32 + q * 8;
          bf16x8 ah = *(const bf16x8*)&Hh[o];
          bf16x8 al = *(const bf16x8*)&Hl[o];
#pragma unroll
          for (int nt = 0; nt < 2; ++nt) {
            acc[mt][nt] = __builtin_amdgcn_mfma_f32_16x16x32_bf16(ah, bh[nt], acc[mt][nt], 0, 0, 0);
            acc[mt][nt] = __builtin_amdgcn_mfma_f32_16x16x32_bf16(al, bh[nt], acc[mt][nt], 0, 0, 0);
            acc[mt][nt] = __builtin_amdgcn_mfma_f32_16x16x32_bf16(ah, bl[nt], acc[mt][nt], 0, 0, 0);
          }
        }
      }
      float b2v[2] = { b2[wbase + r], b2[wbase + 16 + r] };
#pragma unroll
      for (int nt = 0; nt < 2; ++nt) {
        float vmax = NEGV;
#pragma unroll
        for (int mt = 0; mt < 4; ++mt)
#pragma unroll
          for (int ii = 0; ii < 4; ++ii) {
            int mm = mt * 16 + q * 4 + ii;
            float v = fmaxf(acc[mt][nt][ii] + b2v[nt], 0.0f);
            if (mm < cnt) vmax = fmaxf(vmax, v);
          }
        vmax = fmaxf(vmax, __shfl_xor(vmax, 16, 64));
        vmax = fmaxf(vmax, __shfl_xor(vmax, 32, 64));
        if (q == 0)
          out[(size_t)cid * HH + wbase + nt * 16 + r] = (cnt > 0) ? vmax : 0.0f;
      }
    }
    __syncthreads();   // LDS reuse guard before next center
  }
}

// ---------------------------------------------------------------------------
extern "C" void kernel_launch(void* const* d_in, const int* in_sizes, int n_in,
                              void* d_out, int out_size, void* d_ws, size_t ws_size,
                              hipStream_t stream) {
  const float* x   = (const float*)d_in[0];
  const float* pos = (const float*)d_in[1];
  const float* W1  = (const float*)d_in[2];
  const float* b1  = (const float*)d_in[3];
  const float* W2  = (const float*)d_in[4];
  const float* b2  = (const float*)d_in[5];
  float* out = (float*)d_out;
  float* pos_s_out = out + (size_t)BB * MM * HH;

  char* ws = (char*)d_ws;
  float* pos_s_ws = (float*)(ws);                          // 196608 B
  float* pn       = (float*)(ws + 196608);                 // 262144 B
  unsigned short* W1Th = (unsigned short*)(ws + 458752);   // 24576 B
  unsigned short* W1Tl = (unsigned short*)(ws + 483328);   // 24576 B
  unsigned short* W2Th = (unsigned short*)(ws + 507904);   // 32768 B
  unsigned short* W2Tl = (unsigned short*)(ws + 540672);   // 32768 B
  unsigned int* progress = (unsigned int*)(ws + 573440);   // 16*128 B
  unsigned int* claim    = (unsigned int*)(ws + 575488);   // 4 B

  wprep_kernel<<<HH, 128, 0, stream>>>(W1, W2, W1Th, W1Tl, W2Th, W2Tl);
  pn_kernel<<<(BB * NN) / 256, 256, 0, stream>>>(pos, pn);
  init_kernel<<<1, NPROD * PSTRIDE + 64, 0, stream>>>(progress, claim);
  fused_kernel<<<GTOT, 512, 0, stream>>>(pos, x, pn, pos_s_ws, pos_s_out,
                                         W1Th, W1Tl, W2Th, W2Tl, b1, b2, out,
                                         progress, claim);
}